// Round 1
// baseline (98.701 us; speedup 1.0000x reference)
//
#include <hip/hip_runtime.h>
#include <hip/hip_bf16.h>
#include <math.h>

// Sliding-window attention, fp32, flash-style online softmax.
// B=2, S=2048, H=8, D=64, W=128 (W read from device scalar).
// Layout: q/k/v/out [B][S][H][D] -> ((b*S+s)*H+h)*D+d

#define BQ 32        // queries per block
#define KBLK 64      // key-tile rows staged in LDS
#define NTHREADS 256 // 4 waves; 8 lanes per query, each owns 8 dims

__global__ __launch_bounds__(NTHREADS, 4)
void swa_fp32_kernel(const float* __restrict__ q,
                     const float* __restrict__ k,
                     const float* __restrict__ v,
                     const int* __restrict__ wptr,
                     float* __restrict__ out)
{
    constexpr int S = 2048;
    constexpr int H = 8;
    constexpr int D = 64;

    const int W = *wptr;
    const int t = threadIdx.x;

    const int qtiles = S / BQ;              // 64
    const int bid = blockIdx.x;
    const int qt = bid % qtiles;
    const int h  = (bid / qtiles) % H;
    const int b  = bid / (qtiles * H);

    const int i0  = qt * BQ;
    const int qi  = i0 + (t >> 3);          // query row for this thread
    const int d0  = (t & 7) * 8;            // this thread's dim slice

    __shared__ float Kl[KBLK][D];
    __shared__ float Vl[KBLK][D];

    const float scale = 0.125f;             // 1/sqrt(64)

    // Load this thread's 8 q values.
    const size_t qoff = (((size_t)b * S + qi) * H + h) * D + d0;
    float qr[8];
    {
        const float4* qp = (const float4*)(q + qoff);
        float4 a0 = qp[0], a1 = qp[1];
        qr[0]=a0.x; qr[1]=a0.y; qr[2]=a0.z; qr[3]=a0.w;
        qr[4]=a1.x; qr[5]=a1.y; qr[6]=a1.z; qr[7]=a1.w;
    }

    float m = -INFINITY;
    float l = 0.0f;
    float acc[8] = {0.f,0.f,0.f,0.f,0.f,0.f,0.f,0.f};

    int lo = i0 - W;            if (lo < 0)     lo = 0;
    int hi = i0 + BQ - 1 + W;   if (hi > S - 1) hi = S - 1;
    const int kt0 = lo & ~(KBLK - 1);

    const int jlo = qi - W;
    const int jhi = qi + W;

    const size_t bh_off = (size_t)b * S * H * D + (size_t)h * D;   // + j*H*D + d

    for (int kt = kt0; kt <= hi; kt += KBLK) {
        __syncthreads();   // previous tile fully consumed
        // Stage K/V tile: 64 rows x 64 floats, 4 float4 per thread.
        #pragma unroll
        for (int it = 0; it < (KBLK * D / 4) / NTHREADS; ++it) {
            const int f  = t + it * NTHREADS;   // float4 index in tile
            const int jj = f >> 4;              // tile row
            const int dc = (f & 15) << 2;       // float offset in row
            const int j  = kt + jj;
            float4 kv4 = make_float4(0.f,0.f,0.f,0.f);
            float4 vv4 = make_float4(0.f,0.f,0.f,0.f);
            if (j < S) {                        // kt0 >= 0 so j >= 0
                const size_t g = bh_off + (size_t)j * (H * D) + dc;
                kv4 = *(const float4*)(k + g);
                vv4 = *(const float4*)(v + g);
            }
            *(float4*)(&Kl[jj][dc]) = kv4;
            *(float4*)(&Vl[jj][dc]) = vv4;
        }
        __syncthreads();

        // Per-thread skip if this tile is fully outside the query's window.
        if (kt > jhi || kt + KBLK - 1 < jlo) continue;

        for (int jj = 0; jj < KBLK; ++jj) {
            const int j = kt + jj;
            const bool valid = (j >= jlo) && (j <= jhi) && (j < S);

            // Partial dot over this thread's 8 dims (LDS broadcast across groups).
            float pd = 0.f;
            #pragma unroll
            for (int d = 0; d < 8; ++d)
                pd = fmaf(qr[d], Kl[jj][d0 + d], pd);
            // Reduce across the 8-lane group (all lanes end with full dot).
            pd += __shfl_xor(pd, 1);
            pd += __shfl_xor(pd, 2);
            pd += __shfl_xor(pd, 4);

            if (valid) {
                const float s = pd * scale;
                if (s > m) {
                    // Deferred rescale; first valid key: m=-inf -> alpha=0 (correct init).
                    const float alpha = __expf(m - s);
                    l *= alpha;
                    #pragma unroll
                    for (int d = 0; d < 8; ++d) acc[d] *= alpha;
                    m = s;
                }
                const float p = __expf(s - m);
                l += p;
                #pragma unroll
                for (int d = 0; d < 8; ++d)
                    acc[d] = fmaf(p, Vl[jj][d0 + d], acc[d]);
            }
        }
    }

    const float inv_l = 1.0f / l;
    float4 o0, o1;
    o0.x = acc[0]*inv_l; o0.y = acc[1]*inv_l; o0.z = acc[2]*inv_l; o0.w = acc[3]*inv_l;
    o1.x = acc[4]*inv_l; o1.y = acc[5]*inv_l; o1.z = acc[6]*inv_l; o1.w = acc[7]*inv_l;
    float4* op = (float4*)(out + qoff);
    op[0] = o0;
    op[1] = o1;
}

extern "C" void kernel_launch(void* const* d_in, const int* in_sizes, int n_in,
                              void* d_out, int out_size, void* d_ws, size_t ws_size,
                              hipStream_t stream) {
    const float* q = (const float*)d_in[0];
    const float* k = (const float*)d_in[1];
    const float* v = (const float*)d_in[2];
    const int*   w = (const int*)d_in[3];
    float* out = (float*)d_out;

    constexpr int B = 2, S = 2048, H = 8;
    const int nblocks = B * H * (S / BQ);   // 1024
    swa_fp32_kernel<<<dim3(nblocks), dim3(NTHREADS), 0, stream>>>(q, k, v, w, out);
}

// Round 2
// 19.378 us; speedup vs baseline: 5.0935x; 5.0935x over previous
//
#include <hip/hip_runtime.h>
#include <hip/hip_fp16.h>
#include <math.h>

typedef _Float16 half8 __attribute__((ext_vector_type(8)));
typedef _Float16 half4 __attribute__((ext_vector_type(4)));
typedef float f32x4 __attribute__((ext_vector_type(4)));

#define S_LEN 2048
#define NH 8
#define DH 64
#define HD (NH*DH)
#define BQ 64
#define SPAN 320            // BQ + 2*128 (max window)
#define NT 256

// Sliding-window attention, f16 MFMA flash kernel.
// Swapped QK^T: S^T = K*Q^T  (A=K fragment from LDS rows, B=Q fragment in regs)
//   -> lane (c,g) holds scores for query q0+c, keys j0 + {4g+r} u {16+4g+r}.
// PV: O^T = V^T * P^T with permuted MFMA K-axis sigma(8g+e) = 4g+(e&3)+16*(e>>2)
//   so the P fragment is exactly the lane's own 8 probabilities (no repack),
//   and V^T fragments are two ds_read_b64 from the transposed V tile.
__global__ __launch_bounds__(NT, 2)
void swa_mfma(const float* __restrict__ qg, const float* __restrict__ kg,
              const float* __restrict__ vg, const int* __restrict__ wptr,
              float* __restrict__ outg)
{
    __shared__ __align__(16) unsigned short Kl[SPAN * DH];  // [key][dim] f16, 16B-chunk swizzle
    __shared__ __align__(16) unsigned short Vt[DH * SPAN];  // [dim][key] f16, 16B-chunk swizzle

    int W = *wptr; if (W > 128) W = 128;
    const int span = BQ + 2 * W;

    const int t = threadIdx.x;
    // XCD-aware bijective swizzle (gridDim.x = 512, multiple of 8)
    int bid = blockIdx.x;
    bid = (bid & 7) * (gridDim.x >> 3) + (bid >> 3);
    const int qt = bid & 31, h = (bid >> 5) & 7, b = bid >> 8;
    const int i0 = qt * BQ, s0 = i0 - W;

    const float* kbh = kg + (size_t)b * S_LEN * HD + h * DH;
    const float* vbh = vg + (size_t)b * S_LEN * HD + h * DH;

    // ---- stage K: rows [key][64] f16, chunk c of row r stored at chunk (c ^ (r&7)) ----
    for (int cidx = t; cidx < span * 8; cidx += NT) {
        const int koff = cidx >> 3, cr = cidx & 7;
        const int j = s0 + koff;
        const int dst = koff * 64 + ((cr ^ (koff & 7)) << 3);
        half8 hv = {0,0,0,0,0,0,0,0};
        if ((unsigned)j < S_LEN) {
            const float* p = kbh + (size_t)j * HD + cr * 8;
            float4 f0 = *(const float4*)p, f1 = *(const float4*)(p + 4);
            hv[0]=(_Float16)f0.x; hv[1]=(_Float16)f0.y; hv[2]=(_Float16)f0.z; hv[3]=(_Float16)f0.w;
            hv[4]=(_Float16)f1.x; hv[5]=(_Float16)f1.y; hv[6]=(_Float16)f1.z; hv[7]=(_Float16)f1.w;
        }
        *(half8*)(&Kl[dst]) = hv;
    }

    // ---- stage V transposed: Vt[dim][key], in-register 4x4 transpose ----
    for (int task = t; task < span * 4; task += NT) {
        const int dq = task & 15, kq = task >> 4;   // dq: dim-quad 0..15, kq: key-quad
        float rr[4][4];
        #pragma unroll
        for (int jj = 0; jj < 4; ++jj) {
            const int j = s0 + kq * 4 + jj;
            float4 f = {0.f, 0.f, 0.f, 0.f};
            if ((unsigned)j < S_LEN) f = *(const float4*)(vbh + (size_t)j * HD + dq * 4);
            rr[jj][0] = f.x; rr[jj][1] = f.y; rr[jj][2] = f.z; rr[jj][3] = f.w;
        }
        #pragma unroll
        for (int i = 0; i < 4; ++i) {
            const int dim = dq * 4 + i;
            half4 w = { (_Float16)rr[0][i], (_Float16)rr[1][i],
                        (_Float16)rr[2][i], (_Float16)rr[3][i] };
            const int off = dim * SPAN + (((kq >> 1) ^ (dim & 7)) << 3) + ((kq & 1) << 2);
            *(half4*)(&Vt[off]) = w;
        }
    }

    // ---- per-lane Q fragments (scale folded into Q) ----
    const int wid = t >> 6, lane = t & 63, c = lane & 15, g = lane >> 4;
    const int q = i0 + wid * 16 + c;
    const float* qrow = qg + (size_t)b * S_LEN * HD + h * DH + (size_t)q * HD;
    half8 qa0, qa1;
    #pragma unroll
    for (int e = 0; e < 8; ++e) {
        qa0[e] = (_Float16)(qrow[g * 8 + e] * 0.125f);
        qa1[e] = (_Float16)(qrow[32 + g * 8 + e] * 0.125f);
    }

    const int c7 = c & 7;
    const int ch0 = (g ^ c7) << 3;          // K chunk offset (shorts), k-step 0
    const int ch1 = ((g + 4) ^ c7) << 3;    // k-step 1
    int lo = q - W; if (lo < 0) lo = 0;
    int hi = q + W; if (hi > S_LEN - 1) hi = S_LEN - 1;
    const unsigned rng = (unsigned)(hi - lo);

    int ts = wid >> 1;
    const int ts0 = (s0 < 0) ? ((-s0) >> 5) : 0;
    if (ts0 > ts) ts = ts0;
    const int te_w = (16 * wid + 15 + 2 * W) >> 5;
    const int te_s = (S_LEN - 1 - s0) >> 5;
    const int te = te_w < te_s ? te_w : te_s;

    float m = -1e4f, l = 0.f;
    f32x4 o0 = {0,0,0,0}, o1 = {0,0,0,0}, o2 = {0,0,0,0}, o3 = {0,0,0,0};

    __syncthreads();

    for (int t32 = ts; t32 <= te; ++t32) {
        // ---- QK^T (swapped): S^T = K * Q^T ----
        const unsigned short* krow = &Kl[(t32 * 32 + c) * 64];
        half8 k00 = *(const half8*)(krow + ch0);
        half8 k01 = *(const half8*)(krow + ch1);
        half8 k10 = *(const half8*)(krow + 16 * 64 + ch0);
        half8 k11 = *(const half8*)(krow + 16 * 64 + ch1);
        f32x4 st0 = {0,0,0,0}, st1 = {0,0,0,0};
        st0 = __builtin_amdgcn_mfma_f32_16x16x32_f16(k00, qa0, st0, 0, 0, 0);
        st0 = __builtin_amdgcn_mfma_f32_16x16x32_f16(k01, qa1, st0, 0, 0, 0);
        st1 = __builtin_amdgcn_mfma_f32_16x16x32_f16(k10, qa0, st1, 0, 0, 0);
        st1 = __builtin_amdgcn_mfma_f32_16x16x32_f16(k11, qa1, st1, 0, 0, 0);

        // ---- mask + online softmax (lane-local per query) ----
        const int kb = s0 + t32 * 32 + 4 * g;
        float sv0[4], sv1[4];
        #pragma unroll
        for (int r = 0; r < 4; ++r) {
            sv0[r] = ((unsigned)(kb + r - lo) <= rng)      ? st0[r] : -30000.f;
            sv1[r] = ((unsigned)(kb + 16 + r - lo) <= rng) ? st1[r] : -30000.f;
        }
        float tmax = fmaxf(fmaxf(fmaxf(sv0[0], sv0[1]), fmaxf(sv0[2], sv0[3])),
                           fmaxf(fmaxf(sv1[0], sv1[1]), fmaxf(sv1[2], sv1[3])));
        tmax = fmaxf(tmax, __shfl_xor(tmax, 16));
        tmax = fmaxf(tmax, __shfl_xor(tmax, 32));
        const float newm = fmaxf(m, tmax);
        const float alpha = __expf(m - newm);
        m = newm;
        l *= alpha;
        o0 *= alpha; o1 *= alpha; o2 *= alpha; o3 *= alpha;

        float p0[4], p1[4], ls = 0.f;
        #pragma unroll
        for (int r = 0; r < 4; ++r) {
            p0[r] = __expf(sv0[r] - m);
            p1[r] = __expf(sv1[r] - m);
            ls += p0[r] + p1[r];
        }
        l += ls;
        half8 pb;
        #pragma unroll
        for (int r = 0; r < 4; ++r) { pb[r] = (_Float16)p0[r]; pb[4 + r] = (_Float16)p1[r]; }

        // ---- PV: O^T += V^T * P^T (same sigma permutation on K-axis) ----
        const int cb = 4 * t32 + (g >> 1);
        const int off1 = ((cb ^ c7) << 3) + ((g & 1) << 2);
        const int off2 = (((cb + 2) ^ c7) << 3) + ((g & 1) << 2);
#define PV_STEP(DF, OACC) { \
        const unsigned short* vrow = &Vt[(16 * DF + c) * SPAN]; \
        half4 vlo = *(const half4*)(vrow + off1); \
        half4 vhi = *(const half4*)(vrow + off2); \
        half8 vf; \
        vf[0]=vlo[0]; vf[1]=vlo[1]; vf[2]=vlo[2]; vf[3]=vlo[3]; \
        vf[4]=vhi[0]; vf[5]=vhi[1]; vf[6]=vhi[2]; vf[7]=vhi[3]; \
        OACC = __builtin_amdgcn_mfma_f32_16x16x32_f16(vf, pb, OACC, 0, 0, 0); }
        PV_STEP(0, o0)
        PV_STEP(1, o1)
        PV_STEP(2, o2)
        PV_STEP(3, o3)
#undef PV_STEP
    }

    // ---- epilogue: finish l, write O (lane holds q=q0+c, dims 16*df+4g+r) ----
    l += __shfl_xor(l, 16);
    l += __shfl_xor(l, 32);
    const float inv = 1.0f / l;
    float* orow = outg + (size_t)b * S_LEN * HD + h * DH + (size_t)q * HD + 4 * g;
    { float4 w; w.x=o0[0]*inv; w.y=o0[1]*inv; w.z=o0[2]*inv; w.w=o0[3]*inv; *(float4*)(orow)      = w; }
    { float4 w; w.x=o1[0]*inv; w.y=o1[1]*inv; w.z=o1[2]*inv; w.w=o1[3]*inv; *(float4*)(orow + 16) = w; }
    { float4 w; w.x=o2[0]*inv; w.y=o2[1]*inv; w.z=o2[2]*inv; w.w=o2[3]*inv; *(float4*)(orow + 32) = w; }
    { float4 w; w.x=o3[0]*inv; w.y=o3[1]*inv; w.z=o3[2]*inv; w.w=o3[3]*inv; *(float4*)(orow + 48) = w; }
}

extern "C" void kernel_launch(void* const* d_in, const int* in_sizes, int n_in,
                              void* d_out, int out_size, void* d_ws, size_t ws_size,
                              hipStream_t stream) {
    const float* q = (const float*)d_in[0];
    const float* k = (const float*)d_in[1];
    const float* v = (const float*)d_in[2];
    const int*   w = (const int*)d_in[3];
    float* out = (float*)d_out;

    const int nblocks = 2 * NH * (S_LEN / BQ);   // 512
    swa_mfma<<<dim3(nblocks), dim3(NT), 0, stream>>>(q, k, v, w, out);
}